// Round 21
// baseline (297.773 us; speedup 1.0000x reference)
//
#include <hip/hip_runtime.h>
#include <cstdint>

typedef __bf16 bf16;
typedef __attribute__((ext_vector_type(4))) __bf16 bf16x4;
typedef __attribute__((ext_vector_type(8))) __bf16 bf16x8;
typedef __attribute__((ext_vector_type(4))) float f32x4;

#define MFMA16(a, b, c) __builtin_amdgcn_mfma_f32_16x16x32_bf16((a), (b), (c), 0, 0, 0)

// global -> LDS direct copy, 16B per lane; LDS dest is wave-uniform base + lane*16.
static __device__ __forceinline__ void gload16(const void* g, void* l) {
  __builtin_amdgcn_global_load_lds(
      (const __attribute__((address_space(1))) void*)g,
      (__attribute__((address_space(3))) void*)l, 16, 0, 0);
}

// ---------- swizzles (elem-index space; masks touch bits 3..5 only so 16B/8-elem runs stay intact)
#define SWZ128(r, k) ((r) * 128 + ((k) ^ (((r) & 7) << 3)))          // Ks [r][128]
#define SWZP(r, k)   ((r) * 64  + ((k) ^ (((r) & 7) << 3)))          // Pl [r][64]
#define SWZV(r, k)   ((r) * 64  + ((k) ^ (((r) & 7) << 3)))          // Vt [d][64]

// ---------------------------------------------------------------- fp32 -> bf16
__global__ __launch_bounds__(256) void k_convert(const float* __restrict__ in,
                                                 bf16* __restrict__ out, int n4) {
  int i = blockIdx.x * blockDim.x + threadIdx.x;
  if (i >= n4) return;
  float4 v = *(const float4*)&in[(size_t)i * 4];
  bf16x4 o;
  o[0] = (bf16)v.x; o[1] = (bf16)v.y; o[2] = (bf16)v.z; o[3] = (bf16)v.w;
  *(bf16x4*)&out[(size_t)i * 4] = o;
}

// ------------------------------------------- transpose + convert: out[C][R] = in[R][C]
__global__ void k_transpose(const float* __restrict__ in, bf16* __restrict__ out,
                            int R, int C) {
  __shared__ float tile[32][33];
  int bx = blockIdx.x, by = blockIdx.y;
  int tx = threadIdx.x, ty = threadIdx.y;
#pragma unroll
  for (int i = ty; i < 32; i += 8)
    tile[i][tx] = in[(size_t)(by * 32 + i) * C + bx * 32 + tx];
  __syncthreads();
#pragma unroll
  for (int i = ty; i < 32; i += 8)
    out[(size_t)(bx * 32 + i) * R + by * 32 + tx] = (bf16)tile[tx][i];
}

// ---------------------------------- V head-transpose: vtg[hk][d][s] = qkv[s][2560+hk*128+d]
__global__ void k_vtrans(const bf16* __restrict__ qkv, bf16* __restrict__ vtg) {
  __shared__ bf16 tile[32][33];
  int s0 = blockIdx.x * 32, d0 = blockIdx.y * 32, hk = blockIdx.z;
  int tx = threadIdx.x, ty = threadIdx.y;
#pragma unroll
  for (int i = ty; i < 32; i += 8)
    tile[i][tx] = qkv[(size_t)(s0 + i) * 3072 + 2560 + hk * 128 + d0 + tx];
  __syncthreads();
#pragma unroll
  for (int i = ty; i < 32; i += 8)
    vtg[(size_t)hk * 524288 + (size_t)(d0 + i) * 4096 + s0 + tx] = tile[tx][i];
}

// --------------------------------------------------------------- GEMM (m97 structure)
// C[M][N] = A[M][K] * BT[N][K]^T, bf16 in, OutT out. 128x128 tile, BK=32, 4 waves.
template <typename OutT>
__global__ __launch_bounds__(256) void k_gemm(const bf16* __restrict__ A,
                                              const bf16* __restrict__ BT,
                                              OutT* __restrict__ C, int M, int N, int K) {
  __shared__ bf16 As[128 * 32];
  __shared__ bf16 Bs[128 * 32];
  const int tid = threadIdx.x;
  const int wv = tid >> 6, lane = tid & 63;
  const int lr = lane & 15, lg = lane >> 4;
  const int wm = (wv >> 1) * 64, wn = (wv & 1) * 64;
  const int bm = blockIdx.x, bn = blockIdx.y;
  const size_t baseA = (size_t)bm * 128 * K;
  const size_t baseB = (size_t)bn * 128 * K;
  f32x4 acc[4][4] = {};
  for (int kt = 0; kt < K; kt += 32) {
    __syncthreads();
#pragma unroll
    for (int inst = 0; inst < 2; ++inst) {
      int ch = inst * 256 + tid;
      int row = ch >> 2, ko = (ch & 3) * 8;
      gload16(A + baseA + (size_t)row * K + kt + ko, &As[(size_t)(inst * 256 + wv * 64) * 8]);
      gload16(BT + baseB + (size_t)row * K + kt + ko, &Bs[(size_t)(inst * 256 + wv * 64) * 8]);
    }
    __syncthreads();
    bf16x8 af[4], bfr[4];
#pragma unroll
    for (int mi = 0; mi < 4; ++mi) af[mi] = *(const bf16x8*)&As[(wm + mi * 16 + lr) * 32 + lg * 8];
#pragma unroll
    for (int nj = 0; nj < 4; ++nj) bfr[nj] = *(const bf16x8*)&Bs[(wn + nj * 16 + lr) * 32 + lg * 8];
#pragma unroll
    for (int mi = 0; mi < 4; ++mi)
#pragma unroll
      for (int nj = 0; nj < 4; ++nj)
        acc[mi][nj] = MFMA16(af[mi], bfr[nj], acc[mi][nj]);
  }
#pragma unroll
  for (int mi = 0; mi < 4; ++mi)
#pragma unroll
    for (int nj = 0; nj < 4; ++nj)
#pragma unroll
      for (int j = 0; j < 4; ++j) {
        int r = bm * 128 + wm + mi * 16 + lg * 4 + j;
        int c = bn * 128 + wn + nj * 16 + lr;
        C[(size_t)r * N + c] = (OutT)acc[mi][nj][j];
      }
}

// ------------------------------------------ QKV GEMM with fused RMSNorm+RoPE epilogue
// Wave-split by M: 4 waves x 32 rows, each wave owns ALL 128 cols of the head-aligned
// bn tile -> RMS row-sum is 8 in-reg values + 4 shfl_xor; RoPE partner col d^64 is
// acc[mi][nj^4][j] (same lane). bn<16: q heads (qw); 16..19: k heads (kw); 20..23: v plain.
__global__ __launch_bounds__(256) void k_gemm_qkv(const bf16* __restrict__ A,
                                                  const bf16* __restrict__ BT,
                                                  bf16* __restrict__ qkv,
                                                  const float* __restrict__ cosb,
                                                  const float* __restrict__ sinb,
                                                  const float* __restrict__ qw,
                                                  const float* __restrict__ kw) {
  __shared__ bf16 As[128 * 32];
  __shared__ bf16 Bs[128 * 32];
  const int K = 2048;
  const int tid = threadIdx.x;
  const int wv = tid >> 6, lane = tid & 63;
  const int lr = lane & 15, lg = lane >> 4;
  const int wm = wv * 32;  // wave rows (split by M)
  const int bm = blockIdx.x, bn = blockIdx.y;
  const size_t baseA = (size_t)bm * 128 * K;
  const size_t baseB = (size_t)bn * 128 * K;
  f32x4 acc[2][8] = {};
  for (int kt = 0; kt < K; kt += 32) {
    __syncthreads();
#pragma unroll
    for (int inst = 0; inst < 2; ++inst) {
      int ch = inst * 256 + tid;
      int row = ch >> 2, ko = (ch & 3) * 8;
      gload16(A + baseA + (size_t)row * K + kt + ko, &As[(size_t)(inst * 256 + wv * 64) * 8]);
      gload16(BT + baseB + (size_t)row * K + kt + ko, &Bs[(size_t)(inst * 256 + wv * 64) * 8]);
    }
    __syncthreads();
    bf16x8 af[2], bfr[8];
#pragma unroll
    for (int mi = 0; mi < 2; ++mi) af[mi] = *(const bf16x8*)&As[(wm + mi * 16 + lr) * 32 + lg * 8];
#pragma unroll
    for (int nj = 0; nj < 8; ++nj) bfr[nj] = *(const bf16x8*)&Bs[(nj * 16 + lr) * 32 + lg * 8];
#pragma unroll
    for (int mi = 0; mi < 2; ++mi)
#pragma unroll
      for (int nj = 0; nj < 8; ++nj)
        acc[mi][nj] = MFMA16(af[mi], bfr[nj], acc[mi][nj]);
  }

  if (bn < 20) {
    // ---- fused RMSNorm + RoPE (q or k head; head fully inside this tile)
    const float* wt = (bn < 16) ? qw : kw;
    float wreg[8];
#pragma unroll
    for (int nj = 0; nj < 8; ++nj) wreg[nj] = wt[nj * 16 + lr];
#pragma unroll
    for (int mi = 0; mi < 2; ++mi)
#pragma unroll
      for (int j = 0; j < 4; ++j) {
        float s2 = 0.f;
#pragma unroll
        for (int nj = 0; nj < 8; ++nj) s2 += acc[mi][nj][j] * acc[mi][nj][j];
        s2 += __shfl_xor(s2, 1);
        s2 += __shfl_xor(s2, 2);
        s2 += __shfl_xor(s2, 4);
        s2 += __shfl_xor(s2, 8);
        float rinv = rsqrtf(s2 * (1.0f / 128.0f) + 1e-6f);
        int s = bm * 128 + wm + mi * 16 + lg * 4 + j;
        const float* cr = cosb + (size_t)s * 128;
        const float* sr = sinb + (size_t)s * 128;
        float y[8];
#pragma unroll
        for (int nj = 0; nj < 8; ++nj) y[nj] = acc[mi][nj][j] * rinv * wreg[nj];
        bf16* orow = qkv + (size_t)s * 3072 + bn * 128;
#pragma unroll
        for (int nj = 0; nj < 8; ++nj) {
          int d = nj * 16 + lr;
          float rot = (nj < 4) ? -y[nj + 4] : y[nj - 4];
          orow[d] = (bf16)(y[nj] * cr[d] + rot * sr[d]);
        }
      }
  } else {
    // ---- v heads: plain write
#pragma unroll
    for (int mi = 0; mi < 2; ++mi)
#pragma unroll
      for (int nj = 0; nj < 8; ++nj)
#pragma unroll
        for (int j = 0; j < 4; ++j) {
          int r = bm * 128 + wm + mi * 16 + lg * 4 + j;
          int c = bn * 128 + nj * 16 + lr;
          qkv[(size_t)r * 3072 + c] = (bf16)acc[mi][nj][j];
        }
  }
}

// ------------------------------------------------- flash block-causal attention (BLOCK=32)
// Block: one (head, 128-row q-tile, kb-range); 8 waves x 16 rows. KV tiles of 64.
// SWAPPED QK^T; Q pre-scaled by K2; mask branch only on diagonal tiles; pointers bumped.
// SPLIT-K: qt 0..15 full; qt 16..31 two half-range blocks + k_comb merge.
__global__ __launch_bounds__(512, 2) void k_attn(const bf16* __restrict__ qkv,
                                                 const bf16* __restrict__ vtg,
                                                 bf16* __restrict__ out,
                                                 bf16* __restrict__ pO,
                                                 float2* __restrict__ pml) {
  __shared__ bf16 Ks[64 * 128];   // 16 KB, swizzled rows
  __shared__ bf16 Pl[128 * 64];   // 16 KB, wave-private rows
  __shared__ bf16 Vt[128 * 64];   // 16 KB, [d][key] swizzled
  const int tid = threadIdx.x;
  const int wv = tid >> 6, lane = tid & 63;
  const int lr = lane & 15, lg = lane >> 4;
  // grid decode: [0,256) light full tiles; [256,512) half0 of qt=31-..; [512,768) half1
  const int b = blockIdx.x;
  int h, qt, kb0, kb1, tile = 0, half = 0;
  bool split;
  if (b < 256) {
    h = b & 15; qt = b >> 4; kb0 = 0; kb1 = 2 * qt + 2; split = false;
  } else {
    half = (b >= 512);
    int u = b - (half ? 512 : 256);
    h = u & 15; qt = 31 - (u >> 4);
    tile = h * 16 + (qt - 16);
    const int nh = qt + 1;                // half length (nkb = 2qt+2 is even)
    kb0 = half ? nh : 0;
    kb1 = half ? 2 * qt + 2 : nh;
    split = true;
  }
  const int q0 = qt * 128;
  const int hk = h >> 2;
  const int wq = wv * 16;  // 16 q-rows per wave
  const float K2 = 0.12751744f;  // D^-0.5 * log2(e): folded into Q

  // staging geometry (identical linear->swizzled mapping as R10, proven)
  const int chK0 = tid, chK1 = 512 + tid;
  const int rowK0 = chK0 >> 4, rowK1 = chK1 >> 4;
  const int doffK0 = ((chK0 & 15) * 8) ^ ((rowK0 & 7) << 3);
  const int doffK1 = ((chK1 & 15) * 8) ^ ((rowK1 & 7) << 3);
  const int drow0 = chK0 >> 3, drow1 = chK1 >> 3;
  const int koffV0 = ((chK0 & 7) * 8) ^ ((drow0 & 7) << 3);
  const int koffV1 = ((chK1 & 7) * 8) ^ ((drow1 & 7) << 3);
  // pointer-bumped staging sources (advance per iteration)
  const bf16* kp0 = qkv + 2048 + hk * 128 + doffK0 + (size_t)(kb0 * 64 + rowK0) * 3072;
  const bf16* kp1 = qkv + 2048 + hk * 128 + doffK1 + (size_t)(kb0 * 64 + rowK1) * 3072;
  const bf16* vp0 = vtg + (size_t)hk * 524288 + (size_t)drow0 * 4096 + koffV0 + kb0 * 64;
  const bf16* vp1 = vtg + (size_t)hk * 524288 + (size_t)drow1 * 4096 + koffV1 + kb0 * 64;

  // Q fragments in registers, PRE-SCALED by K2 (B-frag: col=lr)
  bf16x8 qf[4];
  {
    const bf16* qrow = qkv + (size_t)(q0 + wq + lr) * 3072 + h * 128 + lg * 8;
#pragma unroll
    for (int kk = 0; kk < 4; ++kk) {
      bf16x8 v = *(const bf16x8*)(qrow + kk * 32);
#pragma unroll
      for (int i = 0; i < 8; ++i) v[i] = (bf16)((float)v[i] * K2);
      qf[kk] = v;
    }
  }

  f32x4 oacc[8] = {};
  float mst = -1e30f, lst = 0.f;  // per-lane scalars for q-row wq+lr
  const int lim = (wq + lr) | 31; // tile-local allowed-key limit for this lane's row

  for (int kb = kb0; kb < kb1; ++kb) {
    __syncthreads();  // prior tile fully consumed; LDS free
    // ---- stage K(t) + V(t) via coalesced gload16 (pointer-bumped)
    gload16(kp0, &Ks[(size_t)(wv * 64) * 8]);
    gload16(kp1, &Ks[(size_t)(512 + wv * 64) * 8]);
    gload16(vp0, &Vt[(size_t)(wv * 64) * 8]);
    gload16(vp1, &Vt[(size_t)(512 + wv * 64) * 8]);
    kp0 += 64 * 3072; kp1 += 64 * 3072; vp0 += 64; vp1 += 64;
    __syncthreads();  // staging visible

    // ---- swapped QK^T: sacc[a][j] = S[key = a*16+lg*4+j][q = wq+lr] (already K2-scaled)
    f32x4 sacc[4] = {};
#pragma unroll
    for (int kk = 0; kk < 4; ++kk) {
      bf16x8 bk[4];
#pragma unroll
      for (int a = 0; a < 4; ++a)
        bk[a] = *(const bf16x8*)&Ks[SWZ128(a * 16 + lr, kk * 32 + lg * 8)];
#pragma unroll
      for (int a = 0; a < 4; ++a)
        sacc[a] = MFMA16(bk[a], qf[kk], sacc[a]);
    }

    // ---- softmax (exp2 domain, defer-rescale THR=8); mask only on diagonal tiles
    float rm = -1e30f;
    if (kb >= 2 * qt) {
      const int koff2 = (kb - 2 * qt) * 64;
#pragma unroll
      for (int a = 0; a < 4; ++a)
#pragma unroll
        for (int j = 0; j < 4; ++j) {
          float sv = sacc[a][j];
          if (koff2 + a * 16 + lg * 4 + j > lim) sv = -1e30f;
          sacc[a][j] = sv;
          rm = fmaxf(rm, sv);
        }
    } else {
#pragma unroll
      for (int a = 0; a < 4; ++a)
#pragma unroll
        for (int j = 0; j < 4; ++j) rm = fmaxf(rm, sacc[a][j]);
    }
    rm = fmaxf(rm, __shfl_xor(rm, 16));
    rm = fmaxf(rm, __shfl_xor(rm, 32));
    if (__any(rm - mst > 8.0f)) {
      float mnew = fmaxf(mst, rm);
      float al = exp2f(mst - mnew);
      mst = mnew;
      lst *= al;
      float alo[4];
#pragma unroll
      for (int j = 0; j < 4; ++j) alo[j] = __shfl(al, lg * 4 + j);
#pragma unroll
      for (int dj = 0; dj < 8; ++dj)
#pragma unroll
        for (int j = 0; j < 4; ++j) oacc[dj][j] *= alo[j];
    }
    float rs = 0.f;
#pragma unroll
    for (int a = 0; a < 4; ++a) {
      bf16x4 pw;
#pragma unroll
      for (int j = 0; j < 4; ++j) {
        float p = exp2f(sacc[a][j] - mst);
        rs += p;
        pw[j] = (bf16)p;
      }
      *(bf16x4*)&Pl[SWZP(wq + lr, a * 16 + lg * 4)] = pw;
    }
    rs += __shfl_xor(rs, 16);
    rs += __shfl_xor(rs, 32);
    lst += rs;

    // ---- PV: O += P V (P wave-private: same-wave RAW, no barrier needed)
#pragma unroll
    for (int kk = 0; kk < 2; ++kk) {
      bf16x8 ap = *(const bf16x8*)&Pl[SWZP(wq + lr, kk * 32 + lg * 8)];
#pragma unroll
      for (int dj = 0; dj < 8; ++dj) {
        bf16x8 bv = *(const bf16x8*)&Vt[SWZV(dj * 16 + lr, kk * 32 + lg * 8)];
        oacc[dj] = MFMA16(ap, bv, oacc[dj]);
      }
    }
  }

  // epilogue: normalize by l; light -> out, split -> partial buffers
  float lrec = 1.0f / lst;
  float linv[4];
#pragma unroll
  for (int j = 0; j < 4; ++j) linv[j] = __shfl(lrec, lg * 4 + j);
  if (!split) {
#pragma unroll
    for (int dj = 0; dj < 8; ++dj)
#pragma unroll
      for (int j = 0; j < 4; ++j) {
        int srow = q0 + wq + lg * 4 + j;
        int d = dj * 16 + lr;
        out[(size_t)srow * 2048 + h * 128 + d] = (bf16)(oacc[dj][j] * linv[j]);
      }
  } else {
    if (lg == 0) pml[((size_t)half * 256 + tile) * 128 + wq + lr] = make_float2(mst, lst);
    bf16* pb = pO + (((size_t)half * 256 + tile) * 128) * 128;
#pragma unroll
    for (int dj = 0; dj < 8; ++dj)
#pragma unroll
      for (int j = 0; j < 4; ++j) {
        int row = wq + lg * 4 + j;
        int d = dj * 16 + lr;
        pb[(size_t)row * 128 + d] = (bf16)(oacc[dj][j] * linv[j]);
      }
  }
}

// ----------------------------------------------- combine split-K partials into attno
__global__ __launch_bounds__(256) void k_comb(const bf16* __restrict__ pO,
                                              const float2* __restrict__ pml,
                                              bf16* __restrict__ attno) {
  const int tile = blockIdx.x;          // h*16 + (qt-16)
  const int h = tile >> 4, qt = 16 + (tile & 15);
  const int t = threadIdx.x;
  const int r = blockIdx.y * 32 + (t >> 3);
  const int d0 = (t & 7) * 16;
  float2 m0 = pml[(size_t)tile * 128 + r];
  float2 m1 = pml[(size_t)(256 + tile) * 128 + r];
  float mm = fmaxf(m0.x, m1.x);
  float w0 = m0.y * exp2f(m0.x - mm);
  float w1 = m1.y * exp2f(m1.x - mm);
  float inv = 1.0f / (w0 + w1);
  w0 *= inv; w1 *= inv;
  const bf16* p0 = pO + ((size_t)tile * 128 + r) * 128 + d0;
  const bf16* p1 = pO + ((size_t)(256 + tile) * 128 + r) * 128 + d0;
  bf16* o = attno + (size_t)(qt * 128 + r) * 2048 + h * 128 + d0;
#pragma unroll
  for (int v = 0; v < 2; ++v) {
    bf16x8 a = *(const bf16x8*)(p0 + v * 8);
    bf16x8 c = *(const bf16x8*)(p1 + v * 8);
    bf16x8 ov;
#pragma unroll
    for (int i = 0; i < 8; ++i) ov[i] = (bf16)((float)a[i] * w0 + (float)c[i] * w1);
    *(bf16x8*)(o + v * 8) = ov;
  }
}

// ---------------------------------------------------------------------------------
extern "C" void kernel_launch(void* const* d_in, const int* in_sizes, int n_in,
                              void* d_out, int out_size, void* d_ws, size_t ws_size,
                              hipStream_t stream) {
  const float* hs = (const float*)d_in[0];
  const float* cosb = (const float*)d_in[1];
  const float* sinb = (const float*)d_in[2];
  const float* w_qkv = (const float*)d_in[3];
  const float* qw = (const float*)d_in[4];
  const float* kw = (const float*)d_in[5];
  const float* w_o = (const float*)d_in[6];
  float* out = (float*)d_out;  // reference output dtype is fp32

  char* ws = (char*)d_ws;
  bf16* qkv   = (bf16*)(ws);                // 4096x3072 bf16          [0, 25165824)
  bf16* hsb   = (bf16*)(ws + 25165824);     // 4096x2048 bf16          [25165824, 41943040)
  bf16* wqkvT = (bf16*)(ws + 41943040);     // 3072x2048 bf16          [41943040, 54525952)
  bf16* woT   = (bf16*)(ws + 41943040);     // 2048x2048 bf16 (reuses wqkvT after gemm1)
  bf16* attno = (bf16*)(ws + 25165824);     // 4096x2048 bf16 (reuses hsb after gemm1)
  bf16* vtg   = (bf16*)(ws + 54525952);     // 4x128x4096 bf16         [54525952, 58720256)
  bf16* pO    = (bf16*)(ws + 58720256);     // [2][256][128][128] bf16 [58720256, 75497472)
  float2* pml = (float2*)(ws + 75497472);   // [2][256][128] float2    [75497472, 76021760)
  // total ws usage: ~72.5 MiB

  k_convert<<<8192, 256, 0, stream>>>(hs, hsb, 2097152);
  k_transpose<<<dim3(96, 64), dim3(32, 8), 0, stream>>>(w_qkv, wqkvT, 2048, 3072);
  k_gemm_qkv<<<dim3(32, 24), 256, 0, stream>>>(hsb, wqkvT, qkv, cosb, sinb, qw, kw);
  k_vtrans<<<dim3(128, 4, 4), dim3(32, 8), 0, stream>>>(qkv, vtg);
  k_transpose<<<dim3(64, 64), dim3(32, 8), 0, stream>>>(w_o, woT, 2048, 2048);
  k_attn<<<768, 512, 0, stream>>>(qkv, vtg, attno, pO, pml);
  k_comb<<<dim3(256, 4), 256, 0, stream>>>(pO, pml, attno);
  k_gemm<float><<<dim3(32, 16), 256, 0, stream>>>(attno, woT, out, 4096, 2048, 2048);
}

// Round 22
// 291.836 us; speedup vs baseline: 1.0203x; 1.0203x over previous
//
#include <hip/hip_runtime.h>
#include <cstdint>

typedef __bf16 bf16;
typedef __attribute__((ext_vector_type(4))) __bf16 bf16x4;
typedef __attribute__((ext_vector_type(8))) __bf16 bf16x8;
typedef __attribute__((ext_vector_type(4))) float f32x4;

#define MFMA16(a, b, c) __builtin_amdgcn_mfma_f32_16x16x32_bf16((a), (b), (c), 0, 0, 0)

// global -> LDS direct copy, 16B per lane; LDS dest is wave-uniform base + lane*16.
static __device__ __forceinline__ void gload16(const void* g, void* l) {
  __builtin_amdgcn_global_load_lds(
      (const __attribute__((address_space(1))) void*)g,
      (__attribute__((address_space(3))) void*)l, 16, 0, 0);
}

// ---------- swizzles (elem-index space; masks touch bits 3..5 only so 16B/8-elem runs stay intact)
#define SWZ128(r, k) ((r) * 128 + ((k) ^ (((r) & 7) << 3)))          // Ks [r][128]
#define SWZP(r, k)   ((r) * 64  + ((k) ^ (((r) & 7) << 3)))          // Pl [r][64]
#define SWZV(r, k)   ((r) * 64  + ((k) ^ (((r) & 7) << 3)))          // Vt [d][64]

// ---------------------------------------------------------------- fp32 -> bf16
__global__ __launch_bounds__(256) void k_convert(const float* __restrict__ in,
                                                 bf16* __restrict__ out, int n4) {
  int i = blockIdx.x * blockDim.x + threadIdx.x;
  if (i >= n4) return;
  float4 v = *(const float4*)&in[(size_t)i * 4];
  bf16x4 o;
  o[0] = (bf16)v.x; o[1] = (bf16)v.y; o[2] = (bf16)v.z; o[3] = (bf16)v.w;
  *(bf16x4*)&out[(size_t)i * 4] = o;
}

// ------------------------------------------- transpose + convert: out[C][R] = in[R][C]
__global__ void k_transpose(const float* __restrict__ in, bf16* __restrict__ out,
                            int R, int C) {
  __shared__ float tile[32][33];
  int bx = blockIdx.x, by = blockIdx.y;
  int tx = threadIdx.x, ty = threadIdx.y;
#pragma unroll
  for (int i = ty; i < 32; i += 8)
    tile[i][tx] = in[(size_t)(by * 32 + i) * C + bx * 32 + tx];
  __syncthreads();
#pragma unroll
  for (int i = ty; i < 32; i += 8)
    out[(size_t)(bx * 32 + i) * R + by * 32 + tx] = (bf16)tile[tx][i];
}

// ---------------------------------- V head-transpose: vtg[hk][d][s] = qkv[s][2560+hk*128+d]
__global__ void k_vtrans(const bf16* __restrict__ qkv, bf16* __restrict__ vtg) {
  __shared__ bf16 tile[32][33];
  int s0 = blockIdx.x * 32, d0 = blockIdx.y * 32, hk = blockIdx.z;
  int tx = threadIdx.x, ty = threadIdx.y;
#pragma unroll
  for (int i = ty; i < 32; i += 8)
    tile[i][tx] = qkv[(size_t)(s0 + i) * 3072 + 2560 + hk * 128 + d0 + tx];
  __syncthreads();
#pragma unroll
  for (int i = ty; i < 32; i += 8)
    vtg[(size_t)hk * 524288 + (size_t)(d0 + i) * 4096 + s0 + tx] = tile[tx][i];
}

// --------------------------------------------------------------- GEMM (m97 structure)
// C[M][N] = A[M][K] * BT[N][K]^T, bf16 in, OutT out. 128x128 tile, BK=32, 4 waves.
template <typename OutT>
__global__ __launch_bounds__(256) void k_gemm(const bf16* __restrict__ A,
                                              const bf16* __restrict__ BT,
                                              OutT* __restrict__ C, int M, int N, int K) {
  __shared__ bf16 As[128 * 32];
  __shared__ bf16 Bs[128 * 32];
  const int tid = threadIdx.x;
  const int wv = tid >> 6, lane = tid & 63;
  const int lr = lane & 15, lg = lane >> 4;
  const int wm = (wv >> 1) * 64, wn = (wv & 1) * 64;
  const int bm = blockIdx.x, bn = blockIdx.y;
  const size_t baseA = (size_t)bm * 128 * K;
  const size_t baseB = (size_t)bn * 128 * K;
  f32x4 acc[4][4] = {};
  for (int kt = 0; kt < K; kt += 32) {
    __syncthreads();
#pragma unroll
    for (int inst = 0; inst < 2; ++inst) {
      int ch = inst * 256 + tid;
      int row = ch >> 2, ko = (ch & 3) * 8;
      gload16(A + baseA + (size_t)row * K + kt + ko, &As[(size_t)(inst * 256 + wv * 64) * 8]);
      gload16(BT + baseB + (size_t)row * K + kt + ko, &Bs[(size_t)(inst * 256 + wv * 64) * 8]);
    }
    __syncthreads();
    bf16x8 af[4], bfr[4];
#pragma unroll
    for (int mi = 0; mi < 4; ++mi) af[mi] = *(const bf16x8*)&As[(wm + mi * 16 + lr) * 32 + lg * 8];
#pragma unroll
    for (int nj = 0; nj < 4; ++nj) bfr[nj] = *(const bf16x8*)&Bs[(wn + nj * 16 + lr) * 32 + lg * 8];
#pragma unroll
    for (int mi = 0; mi < 4; ++mi)
#pragma unroll
      for (int nj = 0; nj < 4; ++nj)
        acc[mi][nj] = MFMA16(af[mi], bfr[nj], acc[mi][nj]);
  }
#pragma unroll
  for (int mi = 0; mi < 4; ++mi)
#pragma unroll
    for (int nj = 0; nj < 4; ++nj)
#pragma unroll
      for (int j = 0; j < 4; ++j) {
        int r = bm * 128 + wm + mi * 16 + lg * 4 + j;
        int c = bn * 128 + wn + nj * 16 + lr;
        C[(size_t)r * N + c] = (OutT)acc[mi][nj][j];
      }
}

// ----------------------------------------------------- RMSNorm + RoPE (q,k heads), in place
__global__ __launch_bounds__(256) void k_rmsrope(bf16* __restrict__ qkv,
                                                 const float* __restrict__ cosb,
                                                 const float* __restrict__ sinb,
                                                 const float* __restrict__ qw,
                                                 const float* __restrict__ kw) {
  int row = blockIdx.x * 4 + (threadIdx.x >> 6);
  int lane = threadIdx.x & 63;
  int s = row / 20, hd = row % 20;
  bool isq = hd < 16;
  int col = isq ? hd * 128 : 2048 + (hd - 16) * 128;
  bf16* p = qkv + (size_t)s * 3072 + col;
  float x1 = (float)p[lane], x2 = (float)p[lane + 64];
  float ss = x1 * x1 + x2 * x2;
#pragma unroll
  for (int m = 32; m; m >>= 1) ss += __shfl_xor(ss, m);
  float r = rsqrtf(ss * (1.0f / 128.0f) + 1e-6f);
  const float* w = isq ? qw : kw;
  float y1 = x1 * r * w[lane], y2 = x2 * r * w[lane + 64];
  float c1 = cosb[s * 128 + lane], c2 = cosb[s * 128 + lane + 64];
  float s1 = sinb[s * 128 + lane], s2 = sinb[s * 128 + lane + 64];
  p[lane] = (bf16)(y1 * c1 - y2 * s1);
  p[lane + 64] = (bf16)(y2 * c2 + y1 * s2);
}

// ------------------------------------------------- flash block-causal attention (BLOCK=32)
// Block: one (head, 128-row q-tile, kb-range); 8 waves x 16 rows. KV tiles of 64.
// SWAPPED QK^T; Q pre-scaled by K2 (softmax needs no per-value scale); mask branch
// taken only on diagonal tiles; staging pointers bumped, not recomputed.
// SPLIT-K: qt 0..15 full; qt 16..31 two half-range blocks + k_comb merge.
__global__ __launch_bounds__(512, 2) void k_attn(const bf16* __restrict__ qkv,
                                                 const bf16* __restrict__ vtg,
                                                 bf16* __restrict__ out,
                                                 bf16* __restrict__ pO,
                                                 float2* __restrict__ pml) {
  __shared__ bf16 Ks[64 * 128];   // 16 KB, swizzled rows
  __shared__ bf16 Pl[128 * 64];   // 16 KB, wave-private rows
  __shared__ bf16 Vt[128 * 64];   // 16 KB, [d][key] swizzled
  const int tid = threadIdx.x;
  const int wv = tid >> 6, lane = tid & 63;
  const int lr = lane & 15, lg = lane >> 4;
  // grid decode: [0,256) light full tiles; [256,512) half0 of qt=31-..; [512,768) half1
  const int b = blockIdx.x;
  int h, qt, kb0, kb1, tile = 0, half = 0;
  bool split;
  if (b < 256) {
    h = b & 15; qt = b >> 4; kb0 = 0; kb1 = 2 * qt + 2; split = false;
  } else {
    half = (b >= 512);
    int u = b - (half ? 512 : 256);
    h = u & 15; qt = 31 - (u >> 4);
    tile = h * 16 + (qt - 16);
    const int nh = qt + 1;                // half length (nkb = 2qt+2 is even)
    kb0 = half ? nh : 0;
    kb1 = half ? 2 * qt + 2 : nh;
    split = true;
  }
  const int q0 = qt * 128;
  const int hk = h >> 2;
  const int wq = wv * 16;  // 16 q-rows per wave
  const float K2 = 0.12751744f;  // D^-0.5 * log2(e): folded into Q

  // staging geometry (identical linear->swizzled mapping as R10, proven)
  const int chK0 = tid, chK1 = 512 + tid;
  const int rowK0 = chK0 >> 4, rowK1 = chK1 >> 4;
  const int doffK0 = ((chK0 & 15) * 8) ^ ((rowK0 & 7) << 3);
  const int doffK1 = ((chK1 & 15) * 8) ^ ((rowK1 & 7) << 3);
  const int drow0 = chK0 >> 3, drow1 = chK1 >> 3;
  const int koffV0 = ((chK0 & 7) * 8) ^ ((drow0 & 7) << 3);
  const int koffV1 = ((chK1 & 7) * 8) ^ ((drow1 & 7) << 3);
  // pointer-bumped staging sources (advance per iteration)
  const bf16* kp0 = qkv + 2048 + hk * 128 + doffK0 + (size_t)(kb0 * 64 + rowK0) * 3072;
  const bf16* kp1 = qkv + 2048 + hk * 128 + doffK1 + (size_t)(kb0 * 64 + rowK1) * 3072;
  const bf16* vp0 = vtg + (size_t)hk * 524288 + (size_t)drow0 * 4096 + koffV0 + kb0 * 64;
  const bf16* vp1 = vtg + (size_t)hk * 524288 + (size_t)drow1 * 4096 + koffV1 + kb0 * 64;

  // Q fragments in registers, PRE-SCALED by K2 (B-frag: col=lr)
  bf16x8 qf[4];
  {
    const bf16* qrow = qkv + (size_t)(q0 + wq + lr) * 3072 + h * 128 + lg * 8;
#pragma unroll
    for (int kk = 0; kk < 4; ++kk) {
      bf16x8 v = *(const bf16x8*)(qrow + kk * 32);
#pragma unroll
      for (int i = 0; i < 8; ++i) v[i] = (bf16)((float)v[i] * K2);
      qf[kk] = v;
    }
  }

  f32x4 oacc[8] = {};
  float mst = -1e30f, lst = 0.f;  // per-lane scalars for q-row wq+lr
  const int lim = (wq + lr) | 31; // tile-local allowed-key limit for this lane's row

  for (int kb = kb0; kb < kb1; ++kb) {
    __syncthreads();  // prior tile fully consumed; LDS free
    // ---- stage K(t) + V(t) via coalesced gload16 (pointer-bumped)
    gload16(kp0, &Ks[(size_t)(wv * 64) * 8]);
    gload16(kp1, &Ks[(size_t)(512 + wv * 64) * 8]);
    gload16(vp0, &Vt[(size_t)(wv * 64) * 8]);
    gload16(vp1, &Vt[(size_t)(512 + wv * 64) * 8]);
    kp0 += 64 * 3072; kp1 += 64 * 3072; vp0 += 64; vp1 += 64;
    __syncthreads();  // staging visible

    // ---- swapped QK^T: sacc[a][j] = S[key = a*16+lg*4+j][q = wq+lr] (already K2-scaled)
    f32x4 sacc[4] = {};
#pragma unroll
    for (int kk = 0; kk < 4; ++kk) {
      bf16x8 bk[4];
#pragma unroll
      for (int a = 0; a < 4; ++a)
        bk[a] = *(const bf16x8*)&Ks[SWZ128(a * 16 + lr, kk * 32 + lg * 8)];
#pragma unroll
      for (int a = 0; a < 4; ++a)
        sacc[a] = MFMA16(bk[a], qf[kk], sacc[a]);
    }

    // ---- softmax (exp2 domain, defer-rescale THR=8); mask only on diagonal tiles
    float rm = -1e30f;
    if (kb >= 2 * qt) {
      const int koff2 = (kb - 2 * qt) * 64;
#pragma unroll
      for (int a = 0; a < 4; ++a)
#pragma unroll
        for (int j = 0; j < 4; ++j) {
          float sv = sacc[a][j];
          if (koff2 + a * 16 + lg * 4 + j > lim) sv = -1e30f;
          sacc[a][j] = sv;
          rm = fmaxf(rm, sv);
        }
    } else {
#pragma unroll
      for (int a = 0; a < 4; ++a)
#pragma unroll
        for (int j = 0; j < 4; ++j) rm = fmaxf(rm, sacc[a][j]);
    }
    rm = fmaxf(rm, __shfl_xor(rm, 16));
    rm = fmaxf(rm, __shfl_xor(rm, 32));
    if (__any(rm - mst > 8.0f)) {
      float mnew = fmaxf(mst, rm);
      float al = exp2f(mst - mnew);
      mst = mnew;
      lst *= al;
      float alo[4];
#pragma unroll
      for (int j = 0; j < 4; ++j) alo[j] = __shfl(al, lg * 4 + j);
#pragma unroll
      for (int dj = 0; dj < 8; ++dj)
#pragma unroll
        for (int j = 0; j < 4; ++j) oacc[dj][j] *= alo[j];
    }
    float rs = 0.f;
#pragma unroll
    for (int a = 0; a < 4; ++a) {
      bf16x4 pw;
#pragma unroll
      for (int j = 0; j < 4; ++j) {
        float p = exp2f(sacc[a][j] - mst);
        rs += p;
        pw[j] = (bf16)p;
      }
      *(bf16x4*)&Pl[SWZP(wq + lr, a * 16 + lg * 4)] = pw;
    }
    rs += __shfl_xor(rs, 16);
    rs += __shfl_xor(rs, 32);
    lst += rs;

    // ---- PV: O += P V (P wave-private: same-wave RAW, no barrier needed)
#pragma unroll
    for (int kk = 0; kk < 2; ++kk) {
      bf16x8 ap = *(const bf16x8*)&Pl[SWZP(wq + lr, kk * 32 + lg * 8)];
#pragma unroll
      for (int dj = 0; dj < 8; ++dj) {
        bf16x8 bv = *(const bf16x8*)&Vt[SWZV(dj * 16 + lr, kk * 32 + lg * 8)];
        oacc[dj] = MFMA16(ap, bv, oacc[dj]);
      }
    }
  }

  // epilogue: normalize by l; light -> out, split -> partial buffers
  float lrec = 1.0f / lst;
  float linv[4];
#pragma unroll
  for (int j = 0; j < 4; ++j) linv[j] = __shfl(lrec, lg * 4 + j);
  if (!split) {
#pragma unroll
    for (int dj = 0; dj < 8; ++dj)
#pragma unroll
      for (int j = 0; j < 4; ++j) {
        int srow = q0 + wq + lg * 4 + j;
        int d = dj * 16 + lr;
        out[(size_t)srow * 2048 + h * 128 + d] = (bf16)(oacc[dj][j] * linv[j]);
      }
  } else {
    if (lg == 0) pml[((size_t)half * 256 + tile) * 128 + wq + lr] = make_float2(mst, lst);
    bf16* pb = pO + (((size_t)half * 256 + tile) * 128) * 128;
#pragma unroll
    for (int dj = 0; dj < 8; ++dj)
#pragma unroll
      for (int j = 0; j < 4; ++j) {
        int row = wq + lg * 4 + j;
        int d = dj * 16 + lr;
        pb[(size_t)row * 128 + d] = (bf16)(oacc[dj][j] * linv[j]);
      }
  }
}

// ----------------------------------------------- combine split-K partials into attno
__global__ __launch_bounds__(256) void k_comb(const bf16* __restrict__ pO,
                                              const float2* __restrict__ pml,
                                              bf16* __restrict__ attno) {
  const int tile = blockIdx.x;          // h*16 + (qt-16)
  const int h = tile >> 4, qt = 16 + (tile & 15);
  const int t = threadIdx.x;
  const int r = blockIdx.y * 32 + (t >> 3);
  const int d0 = (t & 7) * 16;
  float2 m0 = pml[(size_t)tile * 128 + r];
  float2 m1 = pml[(size_t)(256 + tile) * 128 + r];
  float mm = fmaxf(m0.x, m1.x);
  float w0 = m0.y * exp2f(m0.x - mm);
  float w1 = m1.y * exp2f(m1.x - mm);
  float inv = 1.0f / (w0 + w1);
  w0 *= inv; w1 *= inv;
  const bf16* p0 = pO + ((size_t)tile * 128 + r) * 128 + d0;
  const bf16* p1 = pO + ((size_t)(256 + tile) * 128 + r) * 128 + d0;
  bf16* o = attno + (size_t)(qt * 128 + r) * 2048 + h * 128 + d0;
#pragma unroll
  for (int v = 0; v < 2; ++v) {
    bf16x8 a = *(const bf16x8*)(p0 + v * 8);
    bf16x8 c = *(const bf16x8*)(p1 + v * 8);
    bf16x8 ov;
#pragma unroll
    for (int i = 0; i < 8; ++i) ov[i] = (bf16)((float)a[i] * w0 + (float)c[i] * w1);
    *(bf16x8*)(o + v * 8) = ov;
  }
}

// ---------------------------------------------------------------------------------
extern "C" void kernel_launch(void* const* d_in, const int* in_sizes, int n_in,
                              void* d_out, int out_size, void* d_ws, size_t ws_size,
                              hipStream_t stream) {
  const float* hs = (const float*)d_in[0];
  const float* cosb = (const float*)d_in[1];
  const float* sinb = (const float*)d_in[2];
  const float* w_qkv = (const float*)d_in[3];
  const float* qw = (const float*)d_in[4];
  const float* kw = (const float*)d_in[5];
  const float* w_o = (const float*)d_in[6];
  float* out = (float*)d_out;  // reference output dtype is fp32

  char* ws = (char*)d_ws;
  bf16* qkv   = (bf16*)(ws);                // 4096x3072 bf16          [0, 25165824)
  bf16* hsb   = (bf16*)(ws + 25165824);     // 4096x2048 bf16          [25165824, 41943040)
  bf16* wqkvT = (bf16*)(ws + 41943040);     // 3072x2048 bf16          [41943040, 54525952)
  bf16* woT   = (bf16*)(ws + 41943040);     // 2048x2048 bf16 (reuses wqkvT after gemm1)
  bf16* attno = (bf16*)(ws + 25165824);     // 4096x2048 bf16 (reuses hsb after gemm1)
  bf16* vtg   = (bf16*)(ws + 54525952);     // 4x128x4096 bf16         [54525952, 58720256)
  bf16* pO    = (bf16*)(ws + 58720256);     // [2][256][128][128] bf16 [58720256, 75497472)
  float2* pml = (float2*)(ws + 75497472);   // [2][256][128] float2    [75497472, 76021760)
  // total ws usage: ~72.5 MiB

  k_convert<<<8192, 256, 0, stream>>>(hs, hsb, 2097152);
  k_transpose<<<dim3(96, 64), dim3(32, 8), 0, stream>>>(w_qkv, wqkvT, 2048, 3072);
  k_gemm<bf16><<<dim3(32, 24), 256, 0, stream>>>(hsb, wqkvT, qkv, 4096, 3072, 2048);
  k_rmsrope<<<20480, 256, 0, stream>>>(qkv, cosb, sinb, qw, kw);
  k_vtrans<<<dim3(128, 4, 4), dim3(32, 8), 0, stream>>>(qkv, vtg);
  k_transpose<<<dim3(64, 64), dim3(32, 8), 0, stream>>>(w_o, woT, 2048, 2048);
  k_attn<<<768, 512, 0, stream>>>(qkv, vtg, attno, pO, pml);
  k_comb<<<dim3(256, 4), 256, 0, stream>>>(pO, pml, attno);
  k_gemm<float><<<dim3(32, 16), 256, 0, stream>>>(attno, woT, out, 4096, 2048, 2048);
}